// Round 3
// baseline (248.131 us; speedup 1.0000x reference)
//
#include <hip/hip_runtime.h>
#include <type_traits>
#include <utility>

// ---------------- types ----------------
typedef float f32x4 __attribute__((ext_vector_type(4)));
typedef __bf16 bf16x8 __attribute__((ext_vector_type(8)));
typedef short s16x8 __attribute__((ext_vector_type(8)));

// ---- mfma wrapper: robust to builtin operand type (v8 bf16 vs v8 short) ----
template <typename V>
__device__ __forceinline__ f32x4 mfma_call(V a, V b, f32x4 c) {
  return __builtin_amdgcn_mfma_f32_16x16x32_bf16(a, b, c, 0, 0, 0);
}
template <typename V, typename = void>
struct MfmaTakes : std::false_type {};
template <typename V>
struct MfmaTakes<V, std::void_t<decltype(__builtin_amdgcn_mfma_f32_16x16x32_bf16(
    std::declval<V>(), std::declval<V>(), std::declval<f32x4>(), 0, 0, 0))>>
    : std::true_type {};

template <typename = void>
__device__ __forceinline__ f32x4 MFMA16(uint4 a, uint4 b, f32x4 c) {
  if constexpr (MfmaTakes<bf16x8>::value) {
    return mfma_call(__builtin_bit_cast(bf16x8, a), __builtin_bit_cast(bf16x8, b), c);
  } else {
    return mfma_call(__builtin_bit_cast(s16x8, a), __builtin_bit_cast(s16x8, b), c);
  }
}

// ---------------- f32 -> bf16 (RNE) packing ----------------
__device__ __forceinline__ unsigned f2bf(float f) {
  unsigned u = __builtin_bit_cast(unsigned, f);
  return (u + 0x7FFFu + ((u >> 16) & 1u)) >> 16;
}
__device__ __forceinline__ unsigned pk2(float lo, float hi) {
  return f2bf(lo) | (f2bf(hi) << 16);
}
__device__ __forceinline__ uint4 pk8(float4 x, float4 y) {
  return make_uint4(pk2(x.x, x.y), pk2(x.z, x.w), pk2(y.x, y.y), pk2(y.z, y.w));
}

// ---------------- problem constants ----------------
constexpr int TS  = 2304;  // sequence length
constexpr int DH  = 64;    // head dim
constexpr int NBH = 32;    // B*H
constexpr int QTB = 64;    // q rows per block (16 per wave, 4 waves)
constexpr int NQB = TS / QTB;   // 36
constexpr int VSTR = 68;   // V LDS row stride (shorts): 64 + 4 pad
constexpr int PSTR = 40;   // P LDS row stride (shorts): 80B, 16B-aligned
constexpr float SCALE = 0.125f;                 // 1/sqrt(64)
constexpr float L2E   = 1.4426950408889634f;
constexpr float NEGBIG = -3.0e38f;

// L-former block mask ∧ causal att_mask == pure causal (see analysis):
// for cb<=rb, lim=(floor(sqrt(16rb+15))+1)^2 >= 16rb+16 > 16cb, so every
// sub-diagonal block is active; super-diagonal entries die to the causal mask.
__global__ __launch_bounds__(256) void lformer_attn(
    const float* __restrict__ Qm, const float* __restrict__ Km,
    const float* __restrict__ Vm, float* __restrict__ Om) {
  __shared__ short lk[32 * 64];        // K tile, XOR-swizzled 128B rows
  __shared__ short lv[32 * VSTR];      // V tile, padded row-major
  __shared__ short lp[4][16 * PSTR];   // per-wave P buffer

  const int bid = blockIdx.x;
  const int qb  = (NQB - 1) - (bid >> 5);  // heavy q-blocks first
  const int bh  = bid & 31;
  const int tid = threadIdx.x;
  const int w    = tid >> 6;
  const int lane = tid & 63;
  const int g    = lane >> 4;
  const int c16  = lane & 15;

  const size_t base = (size_t)bh * TS * DH;
  const int q0  = qb * QTB;
  const int qrb = q0 + 16 * w;   // this wave's first q row

  // ---- Q fragments, resident for the whole kernel (2 chunks of K=32) ----
  uint4 qf[2];
  {
    const float* qp = Qm + base + (size_t)(qrb + c16) * DH;
#pragma unroll
    for (int cc = 0; cc < 2; ++cc) {
      const int d = cc * 32 + 8 * g;
      float4 x = *(const float4*)(qp + d);
      float4 y = *(const float4*)(qp + d + 4);
      qf[cc] = pk8(x, y);
    }
  }

  f32x4 acc[4] = {};                               // O accum: 4 d-tiles
  float mrow[4] = {NEGBIG, NEGBIG, NEGBIG, NEGBIG};
  float lrow[4] = {0.f, 0.f, 0.f, 0.f};

  const int skv = tid >> 3;        // staging: kv row 0..31
  const int sd  = (tid & 7) * 8;   // staging: d chunk
  const int nkv = (q0 + QTB) / 32; // causal KV extent in 32-tiles

  for (int step = 0; step < nkv; ++step) {
    const int kv0 = step * 32;
    // ---- stage K (swizzled) and V (padded) as bf16 ----
    {
      const float* kp = Km + base + (size_t)(kv0 + skv) * DH + sd;
      float4 kx = *(const float4*)kp;
      float4 ky = *(const float4*)(kp + 4);
      const int ksidx = (skv * 64 + sd) ^ ((skv & 7) * 8);
      *(uint4*)&lk[ksidx] = pk8(kx, ky);

      const float* vp = Vm + base + (size_t)(kv0 + skv) * DH + sd;
      float4 vx = *(const float4*)vp;
      float4 vy = *(const float4*)(vp + 4);
      uint4 pv = pk8(vx, vy);
      *(uint2*)&lv[skv * VSTR + sd]     = make_uint2(pv.x, pv.y);
      *(uint2*)&lv[skv * VSTR + sd + 4] = make_uint2(pv.z, pv.w);
    }
    __syncthreads();

    if (kv0 <= qrb + 15) {   // wave-uniform: tile not fully above diagonal
      // ---- S = Q K^T  (2 n-tiles x 2 K-chunks) ----
      f32x4 s[2];
#pragma unroll
      for (int nt = 0; nt < 2; ++nt) {
        f32x4 sa = {0.f, 0.f, 0.f, 0.f};
#pragma unroll
        for (int cc = 0; cc < 2; ++cc) {
          const int row  = nt * 16 + c16;
          const int sidx = (row * 64 + cc * 32 + g * 8) ^ ((row & 7) * 8);
          uint4 kf = *(const uint4*)&lk[sidx];
          sa = MFMA16(qf[cc], kf, sa);
        }
        s[nt] = sa;
      }
      // ---- scale + causal mask ----
      float sv[2][4];
#pragma unroll
      for (int nt = 0; nt < 2; ++nt) {
        const int kvg = kv0 + nt * 16 + c16;
#pragma unroll
        for (int r = 0; r < 4; ++r) {
          const int qg = qrb + 4 * g + r;
          float x = s[nt][r] * SCALE;
          sv[nt][r] = (kvg > qg) ? NEGBIG : x;
        }
      }
      // ---- online softmax (row groups of 16 lanes) ----
      float pm[4];
#pragma unroll
      for (int r = 0; r < 4; ++r) pm[r] = fmaxf(sv[0][r], sv[1][r]);
#pragma unroll
      for (int m = 1; m <= 8; m <<= 1) {
#pragma unroll
        for (int r = 0; r < 4; ++r) pm[r] = fmaxf(pm[r], __shfl_xor(pm[r], m, 64));
      }
      float al[4], ps[2][4], rs[4];
#pragma unroll
      for (int r = 0; r < 4; ++r) {
        const float mn = fmaxf(mrow[r], pm[r]);
        al[r] = exp2f((mrow[r] - mn) * L2E);
        mrow[r] = mn;
      }
#pragma unroll
      for (int nt = 0; nt < 2; ++nt)
#pragma unroll
        for (int r = 0; r < 4; ++r)
          ps[nt][r] = exp2f((sv[nt][r] - mrow[r]) * L2E);
#pragma unroll
      for (int r = 0; r < 4; ++r) rs[r] = ps[0][r] + ps[1][r];
#pragma unroll
      for (int m = 1; m <= 8; m <<= 1) {
#pragma unroll
        for (int r = 0; r < 4; ++r) rs[r] += __shfl_xor(rs[r], m, 64);
      }
#pragma unroll
      for (int r = 0; r < 4; ++r) lrow[r] = lrow[r] * al[r] + rs[r];
#pragma unroll
      for (int dt = 0; dt < 4; ++dt)
#pragma unroll
        for (int r = 0; r < 4; ++r) acc[dt][r] *= al[r];

      // ---- P -> LDS (C/D layout) -> A-frag layout ----
#pragma unroll
      for (int nt = 0; nt < 2; ++nt)
#pragma unroll
        for (int r = 0; r < 4; ++r)
          lp[w][(4 * g + r) * PSTR + nt * 16 + c16] = (short)f2bf(ps[nt][r]);
      const uint4 pf = *(const uint4*)&lp[w][c16 * PSTR + g * 8];

      // ---- O += P V  (4 d-tiles, K=32 in one mfma each) ----
#pragma unroll
      for (int dt = 0; dt < 4; ++dt) {
        const short* vb = &lv[(8 * g) * VSTR + dt * 16 + c16];
        unsigned v0 = (unsigned short)vb[0]
                    | ((unsigned)(unsigned short)vb[VSTR] << 16);
        unsigned v1 = (unsigned short)vb[2 * VSTR]
                    | ((unsigned)(unsigned short)vb[3 * VSTR] << 16);
        unsigned v2 = (unsigned short)vb[4 * VSTR]
                    | ((unsigned)(unsigned short)vb[5 * VSTR] << 16);
        unsigned v3 = (unsigned short)vb[6 * VSTR]
                    | ((unsigned)(unsigned short)vb[7 * VSTR] << 16);
        acc[dt] = MFMA16(pf, make_uint4(v0, v1, v2, v3), acc[dt]);
      }
    }
    __syncthreads();
  }

  // ---- epilogue: normalize + store (4 rows x 64B contiguous per instr) ----
  float inv[4];
#pragma unroll
  for (int r = 0; r < 4; ++r) inv[r] = 1.0f / lrow[r];
  float* op = Om + base;
#pragma unroll
  for (int dt = 0; dt < 4; ++dt)
#pragma unroll
    for (int r = 0; r < 4; ++r)
      op[(size_t)(qrb + 4 * g + r) * DH + dt * 16 + c16] = acc[dt][r] * inv[r];
}

extern "C" void kernel_launch(void* const* d_in, const int* in_sizes, int n_in,
                              void* d_out, int out_size, void* d_ws, size_t ws_size,
                              hipStream_t stream) {
  (void)in_sizes; (void)n_in; (void)d_ws; (void)ws_size; (void)out_size;
  const float* q = (const float*)d_in[0];
  const float* k = (const float*)d_in[1];
  const float* v = (const float*)d_in[2];
  float* o = (float*)d_out;
  lformer_attn<<<dim3(NQB * NBH), dim3(256), 0, stream>>>(q, k, v, o);
}

// Round 4
// 176.207 us; speedup vs baseline: 1.4082x; 1.4082x over previous
//
#include <hip/hip_runtime.h>
#include <type_traits>
#include <utility>

// ---------------- types ----------------
typedef float f32x4 __attribute__((ext_vector_type(4)));
typedef __bf16 bf16x8 __attribute__((ext_vector_type(8)));
typedef short s16x8 __attribute__((ext_vector_type(8)));

// ---- mfma wrapper: robust to builtin operand type (v8 bf16 vs v8 short) ----
template <typename V>
__device__ __forceinline__ f32x4 mfma_call(V a, V b, f32x4 c) {
  return __builtin_amdgcn_mfma_f32_16x16x32_bf16(a, b, c, 0, 0, 0);
}
template <typename V, typename = void>
struct MfmaTakes : std::false_type {};
template <typename V>
struct MfmaTakes<V, std::void_t<decltype(__builtin_amdgcn_mfma_f32_16x16x32_bf16(
    std::declval<V>(), std::declval<V>(), std::declval<f32x4>(), 0, 0, 0))>>
    : std::true_type {};

template <typename = void>
__device__ __forceinline__ f32x4 MFMA16(uint4 a, uint4 b, f32x4 c) {
  if constexpr (MfmaTakes<bf16x8>::value) {
    return mfma_call(__builtin_bit_cast(bf16x8, a), __builtin_bit_cast(bf16x8, b), c);
  } else {
    return mfma_call(__builtin_bit_cast(s16x8, a), __builtin_bit_cast(s16x8, b), c);
  }
}

// ---------------- f32 -> bf16 via native casts (compiler emits cvt_pk) ----
__device__ __forceinline__ uint4 pk8(float4 x, float4 y) {
  bf16x8 v = {(__bf16)x.x, (__bf16)x.y, (__bf16)x.z, (__bf16)x.w,
              (__bf16)y.x, (__bf16)y.y, (__bf16)y.z, (__bf16)y.w};
  return __builtin_bit_cast(uint4, v);
}
__device__ __forceinline__ unsigned pk2n(float a, float b) {
  unsigned short ua = __builtin_bit_cast(unsigned short, (__bf16)a);
  unsigned short ub = __builtin_bit_cast(unsigned short, (__bf16)b);
  return (unsigned)ua | ((unsigned)ub << 16);
}
__device__ __forceinline__ short bf1(float a) {
  return __builtin_bit_cast(short, (__bf16)a);
}

// ---------------- DPP 16-lane-row reductions (no DS traffic) ----------------
template <int CTRL>
__device__ __forceinline__ float dpp_mov(float x) {
  return __builtin_bit_cast(float, __builtin_amdgcn_update_dpp(
      0, __builtin_bit_cast(int, x), CTRL, 0xF, 0xF, true));
}
__device__ __forceinline__ float rmax16(float x) {
  x = fmaxf(x, dpp_mov<0x121>(x));  // row_ror:1
  x = fmaxf(x, dpp_mov<0x122>(x));  // row_ror:2
  x = fmaxf(x, dpp_mov<0x124>(x));  // row_ror:4
  x = fmaxf(x, dpp_mov<0x128>(x));  // row_ror:8
  return x;
}
__device__ __forceinline__ float rsum16(float x) {
  x += dpp_mov<0x121>(x);
  x += dpp_mov<0x122>(x);
  x += dpp_mov<0x124>(x);
  x += dpp_mov<0x128>(x);
  return x;
}

// ---------------- problem constants ----------------
constexpr int TS  = 2304;
constexpr int DH  = 64;
constexpr int NBH = 32;
constexpr int QTB = 64;          // q rows per block (16 per wave, 4 waves)
constexpr int NQB = TS / QTB;    // 36
constexpr int KVB = 64;          // kv rows per step
constexpr int VTSTR = 72;        // vt row stride (shorts): 144B, 16B-aligned
constexpr int PSTR  = 72;        // lp row stride (shorts)
constexpr float QSCL = 0.125f * 1.4426950408889634f;  // 1/sqrt(64) * log2(e)
constexpr float THR  = 8.0f * 1.4426950408889634f;    // defer-rescale, log2 units
constexpr float NEGBIG = -3.0e38f;

// L-former block mask ∧ causal att_mask == pure causal (see round-0 analysis).
// Scores computed in log2 domain: S' = (Q*QSCL)K^T; softmax uses exp2 direct.
__global__ __launch_bounds__(256) void lformer_attn(
    const float* __restrict__ Qm, const float* __restrict__ Km,
    const float* __restrict__ Vm, float* __restrict__ Om) {
  __shared__ short lk[KVB * 64];        // K tile, XOR-swizzled 128B rows (8 KB)
  __shared__ short vt[64 * VTSTR];      // V tile TRANSPOSED: vt[d][kv] (9 KB)
  __shared__ short lp[4][16 * PSTR];    // per-wave P buffer (9 KB)

  const int bid = blockIdx.x;
  const int qb  = (NQB - 1) - (bid >> 5);  // heavy q-blocks first
  const int bh  = bid & 31;
  const int tid = threadIdx.x;
  const int w    = tid >> 6;
  const int lane = tid & 63;
  const int g    = lane >> 4;
  const int c16  = lane & 15;

  const size_t base = (size_t)bh * TS * DH;
  const int q0  = qb * QTB;
  const int qrb = q0 + 16 * w;   // this wave's first q row

  // ---- Q fragments (pre-scaled by QSCL), resident all kernel ----
  uint4 qf[2];
  {
    const float* qp = Qm + base + (size_t)(qrb + c16) * DH;
#pragma unroll
    for (int cc = 0; cc < 2; ++cc) {
      const int d = cc * 32 + 8 * g;
      float4 x = *(const float4*)(qp + d);
      float4 y = *(const float4*)(qp + d + 4);
      x.x *= QSCL; x.y *= QSCL; x.z *= QSCL; x.w *= QSCL;
      y.x *= QSCL; y.y *= QSCL; y.z *= QSCL; y.w *= QSCL;
      qf[cc] = pk8(x, y);
    }
  }

  f32x4 acc[4] = {};                               // O accum: 4 d-tiles
  float mrow[4] = {NEGBIG, NEGBIG, NEGBIG, NEGBIG};
  float lrow[4] = {0.f, 0.f, 0.f, 0.f};

  // staging maps
  const int krow = tid >> 3;       // K: rows 0..31 (+32 on 2nd iter)
  const int kd   = (tid & 7) * 8;  // K: 8-float chunk
  const int vd   = tid & 63;       // V^T: d lane (coalesced column loads)
  const int vr   = (tid >> 6) * 4; // V^T: 4-row group base

  const int nkv = qb + 1;          // causal extent in 64-tiles

  for (int step = 0; step < nkv; ++step) {
    const int kv0 = step * KVB;
    // ---- stage K (row-major, XOR-swizzled) ----
#pragma unroll
    for (int h = 0; h < 2; ++h) {
      const int row = krow + 32 * h;
      const float* kp = Km + base + (size_t)(kv0 + row) * DH + kd;
      float4 kx = *(const float4*)kp;
      float4 ky = *(const float4*)(kp + 4);
      const int ksidx = (row * 64 + kd) ^ ((row & 7) * 8);
      *(uint4*)&lk[ksidx] = pk8(kx, ky);
    }
    // ---- stage V transposed: vt[d][kv] ----
#pragma unroll
    for (int it = 0; it < 4; ++it) {
      const int r = it * 16 + vr;
      const float* vp = Vm + base + (size_t)(kv0 + r) * DH + vd;
      float a = vp[0], b = vp[DH], c = vp[2 * DH], d2 = vp[3 * DH];
      *(uint2*)&vt[vd * VTSTR + r] = make_uint2(pk2n(a, b), pk2n(c, d2));
    }
    __syncthreads();

    {
      // ---- S = (Q*QSCL) K^T : 4 n-tiles x 2 K-chunks ----
      f32x4 s[4];
#pragma unroll
      for (int nt = 0; nt < 4; ++nt) {
        f32x4 sa = {0.f, 0.f, 0.f, 0.f};
#pragma unroll
        for (int cc = 0; cc < 2; ++cc) {
          const int row  = nt * 16 + c16;
          const int sidx = (row * 64 + cc * 32 + g * 8) ^ ((row & 7) * 8);
          sa = MFMA16(qf[cc], *(const uint4*)&lk[sidx], sa);
        }
        s[nt] = sa;
      }
      // ---- causal mask (scores already in log2 units) ----
      float sv[4][4];
#pragma unroll
      for (int nt = 0; nt < 4; ++nt) {
        const int kvg = kv0 + nt * 16 + c16;
#pragma unroll
        for (int r = 0; r < 4; ++r) {
          const int qg = qrb + 4 * g + r;
          sv[nt][r] = (kvg > qg) ? NEGBIG : s[nt][r];
        }
      }
      // ---- row max (DPP, no DS) ----
      float pm[4];
#pragma unroll
      for (int r = 0; r < 4; ++r) {
        pm[r] = fmaxf(fmaxf(sv[0][r], sv[1][r]), fmaxf(sv[2][r], sv[3][r]));
        pm[r] = rmax16(pm[r]);
      }
      // ---- defer-rescale (T13): skip O/l rescale when max barely grew ----
      const float dm = fmaxf(fmaxf(pm[0] - mrow[0], pm[1] - mrow[1]),
                             fmaxf(pm[2] - mrow[2], pm[3] - mrow[3]));
      if (!__all(dm <= THR)) {
        float al[4];
#pragma unroll
        for (int r = 0; r < 4; ++r) {
          const float mn = fmaxf(mrow[r], pm[r]);
          al[r] = exp2f(mrow[r] - mn);
          mrow[r] = mn;
          lrow[r] *= al[r];
        }
#pragma unroll
        for (int dt = 0; dt < 4; ++dt)
#pragma unroll
          for (int r = 0; r < 4; ++r) acc[dt][r] *= al[r];
      }
      // ---- P = exp2(S - m), row sums ----
      float ps[4][4], rs[4];
#pragma unroll
      for (int nt = 0; nt < 4; ++nt)
#pragma unroll
        for (int r = 0; r < 4; ++r) ps[nt][r] = exp2f(sv[nt][r] - mrow[r]);
#pragma unroll
      for (int r = 0; r < 4; ++r) {
        rs[r] = (ps[0][r] + ps[1][r]) + (ps[2][r] + ps[3][r]);
        lrow[r] += rsum16(rs[r]);
      }
      // ---- P -> per-wave LDS (C/D layout) -> A-frag ----
#pragma unroll
      for (int nt = 0; nt < 4; ++nt)
#pragma unroll
        for (int r = 0; r < 4; ++r)
          lp[w][(4 * g + r) * PSTR + nt * 16 + c16] = bf1(ps[nt][r]);
      uint4 pf[2];
#pragma unroll
      for (int kk = 0; kk < 2; ++kk)
        pf[kk] = *(const uint4*)&lp[w][c16 * PSTR + kk * 32 + g * 8];

      // ---- O += P V : 4 d-tiles x 2 K-chunks, V via vector reads of vt ----
#pragma unroll
      for (int dt = 0; dt < 4; ++dt) {
#pragma unroll
        for (int kk = 0; kk < 2; ++kk) {
          const uint4 vf =
              *(const uint4*)&vt[(dt * 16 + c16) * VTSTR + kk * 32 + 8 * g];
          acc[dt] = MFMA16(pf[kk], vf, acc[dt]);
        }
      }
    }
    __syncthreads();
  }

  // ---- epilogue: normalize + store ----
  float inv[4];
#pragma unroll
  for (int r = 0; r < 4; ++r) inv[r] = 1.0f / lrow[r];
  float* op = Om + base;
#pragma unroll
  for (int dt = 0; dt < 4; ++dt)
#pragma unroll
    for (int r = 0; r < 4; ++r)
      op[(size_t)(qrb + 4 * g + r) * DH + dt * 16 + c16] = acc[dt][r] * inv[r];
}

extern "C" void kernel_launch(void* const* d_in, const int* in_sizes, int n_in,
                              void* d_out, int out_size, void* d_ws, size_t ws_size,
                              hipStream_t stream) {
  (void)in_sizes; (void)n_in; (void)d_ws; (void)ws_size; (void)out_size;
  const float* q = (const float*)d_in[0];
  const float* k = (const float*)d_in[1];
  const float* v = (const float*)d_in[2];
  float* o = (float*)d_out;
  lformer_attn<<<dim3(NQB * NBH), dim3(256), 0, stream>>>(q, k, v, o);
}

// Round 5
// 172.841 us; speedup vs baseline: 1.4356x; 1.0195x over previous
//
#include <hip/hip_runtime.h>
#include <type_traits>
#include <utility>

// ---------------- types ----------------
typedef float f32x4 __attribute__((ext_vector_type(4)));
typedef __bf16 bf16x8 __attribute__((ext_vector_type(8)));
typedef short s16x8 __attribute__((ext_vector_type(8)));

// ---- mfma wrapper: robust to builtin operand type (v8 bf16 vs v8 short) ----
template <typename V>
__device__ __forceinline__ f32x4 mfma_call(V a, V b, f32x4 c) {
  return __builtin_amdgcn_mfma_f32_16x16x32_bf16(a, b, c, 0, 0, 0);
}
template <typename V, typename = void>
struct MfmaTakes : std::false_type {};
template <typename V>
struct MfmaTakes<V, std::void_t<decltype(__builtin_amdgcn_mfma_f32_16x16x32_bf16(
    std::declval<V>(), std::declval<V>(), std::declval<f32x4>(), 0, 0, 0))>>
    : std::true_type {};

template <typename = void>
__device__ __forceinline__ f32x4 MFMA16(uint4 a, uint4 b, f32x4 c) {
  if constexpr (MfmaTakes<bf16x8>::value) {
    return mfma_call(__builtin_bit_cast(bf16x8, a), __builtin_bit_cast(bf16x8, b), c);
  } else {
    return mfma_call(__builtin_bit_cast(s16x8, a), __builtin_bit_cast(s16x8, b), c);
  }
}

// ---------------- f32 -> bf16 via native casts (compiler emits cvt_pk) ----
__device__ __forceinline__ uint4 pk8(float4 x, float4 y) {
  bf16x8 v = {(__bf16)x.x, (__bf16)x.y, (__bf16)x.z, (__bf16)x.w,
              (__bf16)y.x, (__bf16)y.y, (__bf16)y.z, (__bf16)y.w};
  return __builtin_bit_cast(uint4, v);
}
__device__ __forceinline__ unsigned pk2n(float a, float b) {
  unsigned short ua = __builtin_bit_cast(unsigned short, (__bf16)a);
  unsigned short ub = __builtin_bit_cast(unsigned short, (__bf16)b);
  return (unsigned)ua | ((unsigned)ub << 16);
}
__device__ __forceinline__ short bf1(float a) {
  return __builtin_bit_cast(short, (__bf16)a);
}

// ---------------- DPP 16-lane-row max (no DS traffic) ----------------
template <int CTRL>
__device__ __forceinline__ float dpp_mov(float x) {
  return __builtin_bit_cast(float, __builtin_amdgcn_update_dpp(
      0, __builtin_bit_cast(int, x), CTRL, 0xF, 0xF, true));
}
__device__ __forceinline__ float rmax16(float x) {
  x = fmaxf(x, dpp_mov<0x121>(x));  // row_ror:1
  x = fmaxf(x, dpp_mov<0x122>(x));  // row_ror:2
  x = fmaxf(x, dpp_mov<0x124>(x));  // row_ror:4
  x = fmaxf(x, dpp_mov<0x128>(x));  // row_ror:8
  return x;
}

// ---------------- problem constants ----------------
constexpr int TS  = 2304;
constexpr int DH  = 64;
constexpr int NBH = 32;
constexpr int QTB = 64;          // q rows per block (16 per wave, 4 waves)
constexpr int NQB = TS / QTB;    // 36
constexpr int KVB = 64;          // kv rows per step
constexpr int VTSTR = 72;        // vt row stride (shorts): 144B, 16B-aligned
constexpr int PSTR  = 72;        // lp row stride (shorts)
constexpr float QSCL = 0.125f * 1.4426950408889634f;  // 1/sqrt(64) * log2(e)
constexpr float THR  = 8.0f * 1.4426950408889634f;    // defer-rescale, log2 units
constexpr float NEGBIG = -3.0e38f;

// L-former block mask ∧ causal att_mask == pure causal (round-0 analysis).
// Scores in log2 domain; only the last KV tile intersects the diagonal.
__global__ __launch_bounds__(256) void lformer_attn(
    const float* __restrict__ Qm, const float* __restrict__ Km,
    const float* __restrict__ Vm, float* __restrict__ Om) {
  __shared__ short lk[KVB * 64];        // K tile, XOR-swizzled 128B rows (8 KB)
  __shared__ short vt[64 * VTSTR];      // V^T tile: vt[d][kv], kv-blocks swizzled
  __shared__ short lp[4][16 * PSTR];    // per-wave P buffer

  const int bid = blockIdx.x;
  const int qb  = (NQB - 1) - (bid >> 5);  // heavy q-blocks first
  const int bh  = bid & 31;
  const int tid = threadIdx.x;
  const int w    = tid >> 6;
  const int lane = tid & 63;
  const int g    = lane >> 4;
  const int c16  = lane & 15;

  const size_t base = (size_t)bh * TS * DH;
  const int q0  = qb * QTB;
  const int qrb = q0 + 16 * w;   // this wave's first q row

  // ---- Q fragments (pre-scaled by QSCL), resident all kernel ----
  uint4 qf[2];
  {
    const float* qp = Qm + base + (size_t)(qrb + c16) * DH;
#pragma unroll
    for (int cc = 0; cc < 2; ++cc) {
      const int d = cc * 32 + 8 * g;
      float4 x = *(const float4*)(qp + d);
      float4 y = *(const float4*)(qp + d + 4);
      x.x *= QSCL; x.y *= QSCL; x.z *= QSCL; x.w *= QSCL;
      y.x *= QSCL; y.y *= QSCL; y.z *= QSCL; y.w *= QSCL;
      qf[cc] = pk8(x, y);
    }
  }

  const uint4 ONES = make_uint4(0x3F803F80u, 0x3F803F80u, 0x3F803F80u, 0x3F803F80u);

  f32x4 acc[4] = {};                     // O accum: 4 d-tiles
  f32x4 acc_l = {};                      // row-sum accum via ones-MFMA
  float mrow[4] = {NEGBIG, NEGBIG, NEGBIG, NEGBIG};

  // staging maps
  const int krow = tid >> 3;       // K: rows 0..31 (+32 on 2nd iter)
  const int kd   = (tid & 7) * 8;  // K: 8-float chunk
  const int vd   = tid & 63;       // V^T: d lane (coalesced column loads)
  const int vr   = (tid >> 6) * 4; // V^T: 4-row group base
  const int vswz = ((vd >> 3) & 3) << 1;  // write-side kv-block swizzle (even)

  const int nkv = qb + 1;          // causal extent in 64-tiles

  auto stage = [&](int step) {
    const int kv0 = step * KVB;
#pragma unroll
    for (int h = 0; h < 2; ++h) {
      const int row = krow + 32 * h;
      const float* kp = Km + base + (size_t)(kv0 + row) * DH + kd;
      float4 kx = *(const float4*)kp;
      float4 ky = *(const float4*)(kp + 4);
      const int ksidx = (row * 64 + kd) ^ ((row & 7) * 8);
      *(uint4*)&lk[ksidx] = pk8(kx, ky);
    }
#pragma unroll
    for (int it = 0; it < 4; ++it) {
      const int r = it * 16 + vr;                  // kv base, multiple of 4
      const int bp = (r >> 2) ^ vswz;              // swizzled 4-short block
      const float* vp = Vm + base + (size_t)(kv0 + r) * DH + vd;
      float a = vp[0], b = vp[DH], c = vp[2 * DH], d2 = vp[3 * DH];
      *(uint2*)&vt[vd * VTSTR + 4 * bp] = make_uint2(pk2n(a, b), pk2n(c, d2));
    }
  };

  auto compute = [&](int step, auto masked) {
    const int kv0 = step * KVB;
    // ---- S = (Q*QSCL) K^T : 4 n-tiles x 2 K-chunks ----
    f32x4 s[4];
#pragma unroll
    for (int nt = 0; nt < 4; ++nt) {
      f32x4 sa = {0.f, 0.f, 0.f, 0.f};
#pragma unroll
      for (int cc = 0; cc < 2; ++cc) {
        const int row  = nt * 16 + c16;
        const int sidx = (row * 64 + cc * 32 + g * 8) ^ ((row & 7) * 8);
        sa = MFMA16(qf[cc], *(const uint4*)&lk[sidx], sa);
      }
      s[nt] = sa;
    }
    // ---- causal mask only on the diagonal tile ----
    float sv[4][4];
#pragma unroll
    for (int nt = 0; nt < 4; ++nt) {
#pragma unroll
      for (int r = 0; r < 4; ++r) {
        if constexpr (decltype(masked)::value) {
          const int kvg = kv0 + nt * 16 + c16;
          const int qg  = qrb + 4 * g + r;
          sv[nt][r] = (kvg > qg) ? NEGBIG : s[nt][r];
        } else {
          sv[nt][r] = s[nt][r];
        }
      }
    }
    // ---- row max (DPP) ----
    float pm[4];
#pragma unroll
    for (int r = 0; r < 4; ++r) {
      pm[r] = fmaxf(fmaxf(sv[0][r], sv[1][r]), fmaxf(sv[2][r], sv[3][r]));
      pm[r] = rmax16(pm[r]);
    }
    // ---- defer-rescale (T13) ----
    const float dm = fmaxf(fmaxf(pm[0] - mrow[0], pm[1] - mrow[1]),
                           fmaxf(pm[2] - mrow[2], pm[3] - mrow[3]));
    if (!__all(dm <= THR)) {
      float al[4];
#pragma unroll
      for (int r = 0; r < 4; ++r) {
        const float mn = fmaxf(mrow[r], pm[r]);
        al[r] = exp2f(mrow[r] - mn);
        mrow[r] = mn;
      }
#pragma unroll
      for (int dt = 0; dt < 4; ++dt)
#pragma unroll
        for (int r = 0; r < 4; ++r) acc[dt][r] *= al[r];
#pragma unroll
      for (int r = 0; r < 4; ++r) acc_l[r] *= al[r];
    }
    // ---- P = exp2(S - m) ----
    float ps[4][4];
#pragma unroll
    for (int nt = 0; nt < 4; ++nt)
#pragma unroll
      for (int r = 0; r < 4; ++r) ps[nt][r] = exp2f(sv[nt][r] - mrow[r]);
    // ---- P -> per-wave LDS (C/D layout) -> A-frag ----
#pragma unroll
    for (int nt = 0; nt < 4; ++nt)
#pragma unroll
      for (int r = 0; r < 4; ++r)
        lp[w][(4 * g + r) * PSTR + nt * 16 + c16] = bf1(ps[nt][r]);
    uint4 pf[2];
#pragma unroll
    for (int kk = 0; kk < 2; ++kk)
      pf[kk] = *(const uint4*)&lp[w][c16 * PSTR + kk * 32 + g * 8];

    // ---- O += P V (swizzled V^T reads); l += P·1 via ones-MFMA ----
#pragma unroll
    for (int dt = 0; dt < 4; ++dt) {
      const int rswz = ((2 * dt + (c16 >> 3)) & 3) << 1;  // matches write swz
#pragma unroll
      for (int kk = 0; kk < 2; ++kk) {
        const int B = kk * 8 + 2 * g;                     // 4-short block idx
        const uint4 vf =
            *(const uint4*)&vt[(dt * 16 + c16) * VTSTR + 4 * (B ^ rswz)];
        acc[dt] = MFMA16(pf[kk], vf, acc[dt]);
      }
    }
    acc_l = MFMA16(pf[0], ONES, acc_l);
    acc_l = MFMA16(pf[1], ONES, acc_l);
  };

  int step = 0;
  for (; step < nkv - 1; ++step) {
    stage(step);
    __syncthreads();
    compute(step, std::false_type{});
    __syncthreads();
  }
  stage(step);
  __syncthreads();
  compute(step, std::true_type{});

  // ---- epilogue: normalize + store ----
  float inv[4];
#pragma unroll
  for (int r = 0; r < 4; ++r) inv[r] = 1.0f / acc_l[r];
  float* op = Om + base;
#pragma unroll
  for (int dt = 0; dt < 4; ++dt)
#pragma unroll
    for (int r = 0; r < 4; ++r)
      op[(size_t)(qrb + 4 * g + r) * DH + dt * 16 + c16] = acc[dt][r] * inv[r];
}

extern "C" void kernel_launch(void* const* d_in, const int* in_sizes, int n_in,
                              void* d_out, int out_size, void* d_ws, size_t ws_size,
                              hipStream_t stream) {
  (void)in_sizes; (void)n_in; (void)d_ws; (void)ws_size; (void)out_size;
  const float* q = (const float*)d_in[0];
  const float* k = (const float*)d_in[1];
  const float* v = (const float*)d_in[2];
  float* o = (float*)d_out;
  lformer_attn<<<dim3(NQB * NBH), dim3(256), 0, stream>>>(q, k, v, o);
}

// Round 6
// 169.515 us; speedup vs baseline: 1.4638x; 1.0196x over previous
//
#include <hip/hip_runtime.h>
#include <type_traits>
#include <utility>

// ---------------- types ----------------
typedef float f32x4 __attribute__((ext_vector_type(4)));
typedef __bf16 bf16x8 __attribute__((ext_vector_type(8)));
typedef short s16x8 __attribute__((ext_vector_type(8)));

// ---- mfma wrapper: robust to builtin operand type (v8 bf16 vs v8 short) ----
template <typename V>
__device__ __forceinline__ f32x4 mfma_call(V a, V b, f32x4 c) {
  return __builtin_amdgcn_mfma_f32_16x16x32_bf16(a, b, c, 0, 0, 0);
}
template <typename V, typename = void>
struct MfmaTakes : std::false_type {};
template <typename V>
struct MfmaTakes<V, std::void_t<decltype(__builtin_amdgcn_mfma_f32_16x16x32_bf16(
    std::declval<V>(), std::declval<V>(), std::declval<f32x4>(), 0, 0, 0))>>
    : std::true_type {};

template <typename = void>
__device__ __forceinline__ f32x4 MFMA16(uint4 a, uint4 b, f32x4 c) {
  if constexpr (MfmaTakes<bf16x8>::value) {
    return mfma_call(__builtin_bit_cast(bf16x8, a), __builtin_bit_cast(bf16x8, b), c);
  } else {
    return mfma_call(__builtin_bit_cast(s16x8, a), __builtin_bit_cast(s16x8, b), c);
  }
}

// ---------------- f32 -> bf16 via native casts (compiler emits cvt_pk) ----
__device__ __forceinline__ uint4 pk8(float4 x, float4 y) {
  bf16x8 v = {(__bf16)x.x, (__bf16)x.y, (__bf16)x.z, (__bf16)x.w,
              (__bf16)y.x, (__bf16)y.y, (__bf16)y.z, (__bf16)y.w};
  return __builtin_bit_cast(uint4, v);
}
__device__ __forceinline__ unsigned pk2n(float a, float b) {
  unsigned short ua = __builtin_bit_cast(unsigned short, (__bf16)a);
  unsigned short ub = __builtin_bit_cast(unsigned short, (__bf16)b);
  return (unsigned)ua | ((unsigned)ub << 16);
}
__device__ __forceinline__ short bf1(float a) {
  return __builtin_bit_cast(short, (__bf16)a);
}

// ---------------- DPP 16-lane-row max (no DS traffic) ----------------
template <int CTRL>
__device__ __forceinline__ float dpp_mov(float x) {
  return __builtin_bit_cast(float, __builtin_amdgcn_update_dpp(
      0, __builtin_bit_cast(int, x), CTRL, 0xF, 0xF, true));
}
__device__ __forceinline__ float rmax16(float x) {
  x = fmaxf(x, dpp_mov<0x121>(x));  // row_ror:1
  x = fmaxf(x, dpp_mov<0x122>(x));  // row_ror:2
  x = fmaxf(x, dpp_mov<0x124>(x));  // row_ror:4
  x = fmaxf(x, dpp_mov<0x128>(x));  // row_ror:8
  return x;
}

// ---------------- problem constants ----------------
constexpr int TS  = 2304;
constexpr int DH  = 64;
constexpr int NBH = 32;
constexpr int QTB = 64;          // q rows per block (16 per wave, 4 waves)
constexpr int NQB = TS / QTB;    // 36
constexpr int KVB = 64;          // kv rows per step
constexpr int VTSTR = 72;        // vt row stride (shorts): 144B, 16B-aligned
constexpr int PSTR  = 72;        // lp row stride (shorts)
constexpr float QSCL = 0.125f * 1.4426950408889634f;  // 1/sqrt(64) * log2(e)
constexpr float THR  = 8.0f * 1.4426950408889634f;    // defer-rescale, log2 units
constexpr float NEGBIG = -3.0e38f;

// L-former block mask ∧ causal att_mask == pure causal (round-0 analysis).
// Scores in log2 domain; only the last KV tile intersects the diagonal.
// T14 pipeline: issue(t+1) global loads before compute(t); flush to LDS after.
__global__ __launch_bounds__(256) void lformer_attn(
    const float* __restrict__ Qm, const float* __restrict__ Km,
    const float* __restrict__ Vm, float* __restrict__ Om) {
  __shared__ short lk[KVB * 64];        // K tile, XOR-swizzled 128B rows (8 KB)
  __shared__ short vt[64 * VTSTR];      // V^T tile: vt[d][kv], kv-blocks swizzled
  __shared__ short lp[4][16 * PSTR];    // per-wave P buffer

  const int bid = blockIdx.x;
  const int qb  = (NQB - 1) - (bid >> 5);  // heavy q-blocks first
  const int bh  = bid & 31;
  const int tid = threadIdx.x;
  const int w    = tid >> 6;
  const int lane = tid & 63;
  const int g    = lane >> 4;
  const int c16  = lane & 15;

  const size_t base = (size_t)bh * TS * DH;
  const int q0  = qb * QTB;
  const int qrb = q0 + 16 * w;   // this wave's first q row

  // ---- Q fragments (pre-scaled by QSCL), resident all kernel ----
  uint4 qf[2];
  {
    const float* qp = Qm + base + (size_t)(qrb + c16) * DH;
#pragma unroll
    for (int cc = 0; cc < 2; ++cc) {
      const int d = cc * 32 + 8 * g;
      float4 x = *(const float4*)(qp + d);
      float4 y = *(const float4*)(qp + d + 4);
      x.x *= QSCL; x.y *= QSCL; x.z *= QSCL; x.w *= QSCL;
      y.x *= QSCL; y.y *= QSCL; y.z *= QSCL; y.w *= QSCL;
      qf[cc] = pk8(x, y);
    }
  }

  const uint4 ONES = make_uint4(0x3F803F80u, 0x3F803F80u, 0x3F803F80u, 0x3F803F80u);

  f32x4 acc[4] = {};                     // O accum: 4 d-tiles
  f32x4 acc_l = {};                      // row-sum accum via ones-MFMA
  float mrow[4] = {NEGBIG, NEGBIG, NEGBIG, NEGBIG};

  // staging maps
  const int krow = tid >> 3;       // K: rows 0..31 (+32 on 2nd iter)
  const int kd   = (tid & 7) * 8;  // K: 8-float chunk
  const int vd   = tid & 63;       // V^T: d lane (coalesced column loads)
  const int vr   = (tid >> 6) * 4; // V^T: 4-row group base
  const int vswz = ((vd >> 3) & 3) << 1;  // write-side kv-block swizzle (even)

  const int nkv = qb + 1;          // causal extent in 64-tiles

  // ---- T14 prefetch registers ----
  float4 kpre[2][2];
  float  vpre[4][4];

  auto issue = [&](int step) {
    const int kv0 = step * KVB;
#pragma unroll
    for (int h = 0; h < 2; ++h) {
      const float* kp = Km + base + (size_t)(kv0 + krow + 32 * h) * DH + kd;
      kpre[h][0] = *(const float4*)kp;
      kpre[h][1] = *(const float4*)(kp + 4);
    }
#pragma unroll
    for (int it = 0; it < 4; ++it) {
      const float* vp = Vm + base + (size_t)(kv0 + it * 16 + vr) * DH + vd;
      vpre[it][0] = vp[0];
      vpre[it][1] = vp[DH];
      vpre[it][2] = vp[2 * DH];
      vpre[it][3] = vp[3 * DH];
    }
  };

  auto flush = [&]() {
#pragma unroll
    for (int h = 0; h < 2; ++h) {
      const int row = krow + 32 * h;
      const int ksidx = (row * 64 + kd) ^ ((row & 7) * 8);
      *(uint4*)&lk[ksidx] = pk8(kpre[h][0], kpre[h][1]);
    }
#pragma unroll
    for (int it = 0; it < 4; ++it) {
      const int r = it * 16 + vr;                  // kv base, multiple of 4
      const int bp = (r >> 2) ^ vswz;              // swizzled 4-short block
      *(uint2*)&vt[vd * VTSTR + 4 * bp] =
          make_uint2(pk2n(vpre[it][0], vpre[it][1]),
                     pk2n(vpre[it][2], vpre[it][3]));
    }
  };

  auto compute = [&](int step, auto masked) {
    const int kv0 = step * KVB;
    // ---- S = (Q*QSCL) K^T : 4 n-tiles x 2 K-chunks ----
    f32x4 s[4];
#pragma unroll
    for (int nt = 0; nt < 4; ++nt) {
      f32x4 sa = {0.f, 0.f, 0.f, 0.f};
#pragma unroll
      for (int cc = 0; cc < 2; ++cc) {
        const int row  = nt * 16 + c16;
        const int sidx = (row * 64 + cc * 32 + g * 8) ^ ((row & 7) * 8);
        sa = MFMA16(qf[cc], *(const uint4*)&lk[sidx], sa);
      }
      s[nt] = sa;
    }
    // ---- causal mask only on the diagonal tile ----
    float sv[4][4];
#pragma unroll
    for (int nt = 0; nt < 4; ++nt) {
#pragma unroll
      for (int r = 0; r < 4; ++r) {
        if constexpr (decltype(masked)::value) {
          const int kvg = kv0 + nt * 16 + c16;
          const int qg  = qrb + 4 * g + r;
          sv[nt][r] = (kvg > qg) ? NEGBIG : s[nt][r];
        } else {
          sv[nt][r] = s[nt][r];
        }
      }
    }
    // ---- row max (DPP) ----
    float pm[4];
#pragma unroll
    for (int r = 0; r < 4; ++r) {
      pm[r] = fmaxf(fmaxf(sv[0][r], sv[1][r]), fmaxf(sv[2][r], sv[3][r]));
      pm[r] = rmax16(pm[r]);
    }
    // ---- defer-rescale (T13) ----
    const float dm = fmaxf(fmaxf(pm[0] - mrow[0], pm[1] - mrow[1]),
                           fmaxf(pm[2] - mrow[2], pm[3] - mrow[3]));
    if (!__all(dm <= THR)) {
      float al[4];
#pragma unroll
      for (int r = 0; r < 4; ++r) {
        const float mn = fmaxf(mrow[r], pm[r]);
        al[r] = exp2f(mrow[r] - mn);
        mrow[r] = mn;
      }
#pragma unroll
      for (int dt = 0; dt < 4; ++dt)
#pragma unroll
        for (int r = 0; r < 4; ++r) acc[dt][r] *= al[r];
#pragma unroll
      for (int r = 0; r < 4; ++r) acc_l[r] *= al[r];
    }
    // ---- P = exp2(S - m) ----
    float ps[4][4];
#pragma unroll
    for (int nt = 0; nt < 4; ++nt)
#pragma unroll
      for (int r = 0; r < 4; ++r) ps[nt][r] = exp2f(sv[nt][r] - mrow[r]);
    // ---- P -> per-wave LDS (C/D layout) -> A-frag ----
#pragma unroll
    for (int nt = 0; nt < 4; ++nt)
#pragma unroll
      for (int r = 0; r < 4; ++r)
        lp[w][(4 * g + r) * PSTR + nt * 16 + c16] = bf1(ps[nt][r]);
    uint4 pf[2];
#pragma unroll
    for (int kk = 0; kk < 2; ++kk)
      pf[kk] = *(const uint4*)&lp[w][c16 * PSTR + kk * 32 + g * 8];

    // ---- O += P V (swizzled V^T reads); l += P·1 via ones-MFMA ----
#pragma unroll
    for (int dt = 0; dt < 4; ++dt) {
      const int rswz = ((2 * dt + (c16 >> 3)) & 3) << 1;  // matches write swz
#pragma unroll
      for (int kk = 0; kk < 2; ++kk) {
        const int B = kk * 8 + 2 * g;                     // 4-short block idx
        const uint4 vf =
            *(const uint4*)&vt[(dt * 16 + c16) * VTSTR + 4 * (B ^ rswz)];
        acc[dt] = MFMA16(pf[kk], vf, acc[dt]);
      }
    }
    acc_l = MFMA16(pf[0], ONES, acc_l);
    acc_l = MFMA16(pf[1], ONES, acc_l);
  };

  // ---- pipelined main loop ----
  issue(0);
  int step = 0;
  for (; step < nkv - 1; ++step) {
    flush();                       // cvt + LDS write of tile `step`
    __syncthreads();               // LDS ready for all waves
    issue(step + 1);               // next tile's loads fly under compute
    compute(step, std::false_type{});
    __syncthreads();               // LDS consumed; safe to overwrite
  }
  flush();
  __syncthreads();
  compute(step, std::true_type{});

  // ---- epilogue: normalize + store ----
  float inv[4];
#pragma unroll
  for (int r = 0; r < 4; ++r) inv[r] = 1.0f / acc_l[r];
  float* op = Om + base;
#pragma unroll
  for (int dt = 0; dt < 4; ++dt)
#pragma unroll
    for (int r = 0; r < 4; ++r)
      op[(size_t)(qrb + 4 * g + r) * DH + dt * 16 + c16] = acc[dt][r] * inv[r];
}

extern "C" void kernel_launch(void* const* d_in, const int* in_sizes, int n_in,
                              void* d_out, int out_size, void* d_ws, size_t ws_size,
                              hipStream_t stream) {
  (void)in_sizes; (void)n_in; (void)d_ws; (void)ws_size; (void)out_size;
  const float* q = (const float*)d_in[0];
  const float* k = (const float*)d_in[1];
  const float* v = (const float*)d_in[2];
  float* o = (float*)d_out;
  lformer_attn<<<dim3(NQB * NBH), dim3(256), 0, stream>>>(q, k, v, o);
}

// Round 7
// 168.641 us; speedup vs baseline: 1.4714x; 1.0052x over previous
//
#include <hip/hip_runtime.h>
#include <type_traits>
#include <utility>

// ---------------- types ----------------
typedef float f32x4 __attribute__((ext_vector_type(4)));
typedef __bf16 bf16x8 __attribute__((ext_vector_type(8)));
typedef short s16x8 __attribute__((ext_vector_type(8)));

// ---- mfma wrapper: robust to builtin operand type (v8 bf16 vs v8 short) ----
template <typename V>
__device__ __forceinline__ f32x4 mfma_call(V a, V b, f32x4 c) {
  return __builtin_amdgcn_mfma_f32_16x16x32_bf16(a, b, c, 0, 0, 0);
}
template <typename V, typename = void>
struct MfmaTakes : std::false_type {};
template <typename V>
struct MfmaTakes<V, std::void_t<decltype(__builtin_amdgcn_mfma_f32_16x16x32_bf16(
    std::declval<V>(), std::declval<V>(), std::declval<f32x4>(), 0, 0, 0))>>
    : std::true_type {};

template <typename = void>
__device__ __forceinline__ f32x4 MFMA16(uint4 a, uint4 b, f32x4 c) {
  if constexpr (MfmaTakes<bf16x8>::value) {
    return mfma_call(__builtin_bit_cast(bf16x8, a), __builtin_bit_cast(bf16x8, b), c);
  } else {
    return mfma_call(__builtin_bit_cast(s16x8, a), __builtin_bit_cast(s16x8, b), c);
  }
}

// ---------------- f32 -> bf16 via native casts (compiler emits cvt_pk) ----
__device__ __forceinline__ uint4 pk8(float4 x, float4 y) {
  bf16x8 v = {(__bf16)x.x, (__bf16)x.y, (__bf16)x.z, (__bf16)x.w,
              (__bf16)y.x, (__bf16)y.y, (__bf16)y.z, (__bf16)y.w};
  return __builtin_bit_cast(uint4, v);
}
__device__ __forceinline__ unsigned pk2n(float a, float b) {
  unsigned short ua = __builtin_bit_cast(unsigned short, (__bf16)a);
  unsigned short ub = __builtin_bit_cast(unsigned short, (__bf16)b);
  return (unsigned)ua | ((unsigned)ub << 16);
}
__device__ __forceinline__ short bf1(float a) {
  return __builtin_bit_cast(short, (__bf16)a);
}

// ---------------- DPP 16-lane-row max (no DS traffic) ----------------
template <int CTRL>
__device__ __forceinline__ float dpp_mov(float x) {
  return __builtin_bit_cast(float, __builtin_amdgcn_update_dpp(
      0, __builtin_bit_cast(int, x), CTRL, 0xF, 0xF, true));
}
__device__ __forceinline__ float rmax16(float x) {
  x = fmaxf(x, dpp_mov<0x121>(x));  // row_ror:1
  x = fmaxf(x, dpp_mov<0x122>(x));  // row_ror:2
  x = fmaxf(x, dpp_mov<0x124>(x));  // row_ror:4
  x = fmaxf(x, dpp_mov<0x128>(x));  // row_ror:8
  return x;
}

// ---------------- problem constants ----------------
constexpr int TS  = 2304;
constexpr int DH  = 64;
constexpr int QTB = 128;         // q rows per block (16 per wave, 8 waves)
constexpr int NQB = TS / QTB;    // 18
constexpr int KVB = 64;          // kv rows per step
constexpr int VTSTR = 72;        // vt row stride (shorts): 144B, 16B-aligned
constexpr int PSTR  = 72;        // lp row stride (shorts)
constexpr float QSCL = 0.125f * 1.4426950408889634f;  // 1/sqrt(64) * log2(e)
constexpr float THR  = 8.0f * 1.4426950408889634f;    // defer-rescale, log2 units
constexpr float NEGBIG = -3.0e38f;

// L-former block mask ∧ causal att_mask == pure causal (round-0 analysis).
// Scores in log2 domain. Double-buffered LDS, ONE barrier per kv step:
//   issue(t+1) -> compute(t, buf) -> flush(t+1, buf^1) -> barrier
// Writers of buf^1 are always >=1 barrier after buf^1's last readers.
__global__ __launch_bounds__(512, 4) void lformer_attn(
    const float* __restrict__ Qm, const float* __restrict__ Km,
    const float* __restrict__ Vm, float* __restrict__ Om) {
  __shared__ short lk[2][KVB * 64];     // K tiles, XOR-swizzled 128B rows (16 KB)
  __shared__ short vt[2][64 * VTSTR];   // V^T tiles: vt[d][kv] swizzled (18 KB)
  __shared__ short lp[8][16 * PSTR];    // per-wave P buffer (18 KB)

  const int bid = blockIdx.x;
  const int qb  = (NQB - 1) - (bid >> 5);  // heavy q-blocks first
  const int bh  = bid & 31;
  const int tid = threadIdx.x;
  const int w    = tid >> 6;     // 0..7
  const int lane = tid & 63;
  const int g    = lane >> 4;
  const int c16  = lane & 15;

  const size_t base = (size_t)bh * TS * DH;
  const int q0  = qb * QTB;
  const int qrb = q0 + 16 * w;   // this wave's first q row

  // staging maps (512 threads)
  const int krow = tid >> 3;        // K: rows 0..63
  const int kd   = (tid & 7) * 8;   // K: 8-float chunk
  const int vd   = lane;            // V^T: d lane (coalesced column loads)
  const int vr   = (tid >> 6) * 4;  // V^T: 4-row quad base (0..28)
  const int vswz = ((vd >> 3) & 3) << 1;  // write-side kv-block swizzle (even)

  const int nkv = (q0 + QTB) / KVB;       // 2*qb + 2

  // ---- T14 prefetch registers ----
  float4 kpre[2];
  float  vpre[2][4];

  auto issue = [&](int step) {
    const int kv0 = step * KVB;
    const float* kp = Km + base + (size_t)(kv0 + krow) * DH + kd;
    kpre[0] = *(const float4*)kp;
    kpre[1] = *(const float4*)(kp + 4);
#pragma unroll
    for (int it = 0; it < 2; ++it) {
      const float* vp = Vm + base + (size_t)(kv0 + it * 32 + vr) * DH + vd;
      vpre[it][0] = vp[0];
      vpre[it][1] = vp[DH];
      vpre[it][2] = vp[2 * DH];
      vpre[it][3] = vp[3 * DH];
    }
  };

  auto flush = [&](int buf) {
    const int ksidx = (krow * 64 + kd) ^ ((krow & 7) * 8);
    *(uint4*)&lk[buf][ksidx] = pk8(kpre[0], kpre[1]);
#pragma unroll
    for (int it = 0; it < 2; ++it) {
      const int r = it * 32 + vr;          // kv quad base
      const int bp = (r >> 2) ^ vswz;      // swizzled 4-short block
      *(uint2*)&vt[buf][vd * VTSTR + 4 * bp] =
          make_uint2(pk2n(vpre[it][0], vpre[it][1]),
                     pk2n(vpre[it][2], vpre[it][3]));
    }
  };

  // ---- Q fragments (pre-scaled by QSCL), resident all kernel ----
  issue(0);                               // K/V loads fly under Q packing
  uint4 qf[2];
  {
    const float* qp = Qm + base + (size_t)(qrb + c16) * DH;
#pragma unroll
    for (int cc = 0; cc < 2; ++cc) {
      const int d = cc * 32 + 8 * g;
      float4 x = *(const float4*)(qp + d);
      float4 y = *(const float4*)(qp + d + 4);
      x.x *= QSCL; x.y *= QSCL; x.z *= QSCL; x.w *= QSCL;
      y.x *= QSCL; y.y *= QSCL; y.z *= QSCL; y.w *= QSCL;
      qf[cc] = pk8(x, y);
    }
  }

  const uint4 ONES = make_uint4(0x3F803F80u, 0x3F803F80u, 0x3F803F80u, 0x3F803F80u);

  f32x4 acc[4] = {};                     // O accum: 4 d-tiles
  f32x4 acc_l = {};                      // row-sum accum via ones-MFMA
  float mrow[4] = {NEGBIG, NEGBIG, NEGBIG, NEGBIG};

  auto compute = [&](int step, int buf, auto masked) {
    const int kv0 = step * KVB;
    // ---- S = (Q*QSCL) K^T : 4 n-tiles x 2 K-chunks ----
    f32x4 s[4];
#pragma unroll
    for (int nt = 0; nt < 4; ++nt) {
      f32x4 sa = {0.f, 0.f, 0.f, 0.f};
#pragma unroll
      for (int cc = 0; cc < 2; ++cc) {
        const int row  = nt * 16 + c16;
        const int sidx = (row * 64 + cc * 32 + g * 8) ^ ((row & 7) * 8);
        sa = MFMA16(qf[cc], *(const uint4*)&lk[buf][sidx], sa);
      }
      s[nt] = sa;
    }
    // ---- causal mask only where the tile crosses this wave's diagonal ----
    float sv[4][4];
#pragma unroll
    for (int nt = 0; nt < 4; ++nt) {
#pragma unroll
      for (int r = 0; r < 4; ++r) {
        if constexpr (decltype(masked)::value) {
          const int kvg = kv0 + nt * 16 + c16;
          const int qg  = qrb + 4 * g + r;
          sv[nt][r] = (kvg > qg) ? NEGBIG : s[nt][r];
        } else {
          sv[nt][r] = s[nt][r];
        }
      }
    }
    // ---- row max (DPP) ----
    float pm[4];
#pragma unroll
    for (int r = 0; r < 4; ++r) {
      pm[r] = fmaxf(fmaxf(sv[0][r], sv[1][r]), fmaxf(sv[2][r], sv[3][r]));
      pm[r] = rmax16(pm[r]);
    }
    // ---- defer-rescale (T13) ----
    const float dm = fmaxf(fmaxf(pm[0] - mrow[0], pm[1] - mrow[1]),
                           fmaxf(pm[2] - mrow[2], pm[3] - mrow[3]));
    if (!__all(dm <= THR)) {
      float al[4];
#pragma unroll
      for (int r = 0; r < 4; ++r) {
        const float mn = fmaxf(mrow[r], pm[r]);
        al[r] = exp2f(mrow[r] - mn);
        mrow[r] = mn;
      }
#pragma unroll
      for (int dt = 0; dt < 4; ++dt)
#pragma unroll
        for (int r = 0; r < 4; ++r) acc[dt][r] *= al[r];
#pragma unroll
      for (int r = 0; r < 4; ++r) acc_l[r] *= al[r];
    }
    // ---- P = exp2(S - m) ----
    float ps[4][4];
#pragma unroll
    for (int nt = 0; nt < 4; ++nt)
#pragma unroll
      for (int r = 0; r < 4; ++r) ps[nt][r] = exp2f(sv[nt][r] - mrow[r]);
    // ---- P -> per-wave LDS (C/D layout) -> A-frag ----
#pragma unroll
    for (int nt = 0; nt < 4; ++nt)
#pragma unroll
      for (int r = 0; r < 4; ++r)
        lp[w][(4 * g + r) * PSTR + nt * 16 + c16] = bf1(ps[nt][r]);
    uint4 pf[2];
#pragma unroll
    for (int kk = 0; kk < 2; ++kk)
      pf[kk] = *(const uint4*)&lp[w][c16 * PSTR + kk * 32 + g * 8];

    // ---- O += P V (swizzled V^T reads); l += P·1 via ones-MFMA ----
#pragma unroll
    for (int dt = 0; dt < 4; ++dt) {
      const int rswz = ((2 * dt + (c16 >> 3)) & 3) << 1;  // matches write swz
#pragma unroll
      for (int kk = 0; kk < 2; ++kk) {
        const int B = kk * 8 + 2 * g;                     // 4-short block idx
        const uint4 vf =
            *(const uint4*)&vt[buf][(dt * 16 + c16) * VTSTR + 4 * (B ^ rswz)];
        acc[dt] = MFMA16(pf[kk], vf, acc[dt]);
      }
    }
    acc_l = MFMA16(pf[0], ONES, acc_l);
    acc_l = MFMA16(pf[1], ONES, acc_l);
  };

  // ---- pipelined main loop: one barrier per step ----
  flush(0);
  __syncthreads();
  int buf = 0;
  for (int step = 0; step < nkv - 1; ++step) {
    issue(step + 1);
    // all waves active for step < nkv-1; mask only if tile crosses diagonal
    if (step * KVB + KVB - 1 > qrb) compute(step, buf, std::true_type{});
    else                            compute(step, buf, std::false_type{});
    flush(buf ^ 1);
    __syncthreads();
    buf ^= 1;
  }
  {
    const int step = nkv - 1;               // last tile: waves 0-3 idle
    if (step * KVB <= qrb + 15) compute(step, buf, std::true_type{});
  }

  // ---- epilogue: normalize + store ----
  float inv[4];
#pragma unroll
  for (int r = 0; r < 4; ++r) inv[r] = 1.0f / acc_l[r];
  float* op = Om + base;
#pragma unroll
  for (int dt = 0; dt < 4; ++dt)
#pragma unroll
    for (int r = 0; r < 4; ++r)
      op[(size_t)(qrb + 4 * g + r) * DH + dt * 16 + c16] = acc[dt][r] * inv[r];
}

extern "C" void kernel_launch(void* const* d_in, const int* in_sizes, int n_in,
                              void* d_out, int out_size, void* d_ws, size_t ws_size,
                              hipStream_t stream) {
  (void)in_sizes; (void)n_in; (void)d_ws; (void)ws_size; (void)out_size;
  const float* q = (const float*)d_in[0];
  const float* k = (const float*)d_in[1];
  const float* v = (const float*)d_in[2];
  float* o = (float*)d_out;
  lformer_attn<<<dim3(NQB * 32), dim3(512), 0, stream>>>(q, k, v, o);
}

// Round 8
// 166.781 us; speedup vs baseline: 1.4878x; 1.0112x over previous
//
#include <hip/hip_runtime.h>
#include <type_traits>
#include <utility>

// ---------------- types ----------------
typedef float f32x4  __attribute__((ext_vector_type(4)));
typedef float f32x16 __attribute__((ext_vector_type(16)));
typedef __bf16 bf16x8 __attribute__((ext_vector_type(8)));
typedef short  s16x8  __attribute__((ext_vector_type(8)));

// ---- mfma 32x32x16 wrapper: robust to builtin operand type ----
template <typename V>
__device__ __forceinline__ f32x16 mfma32_call(V a, V b, f32x16 c) {
  return __builtin_amdgcn_mfma_f32_32x32x16_bf16(a, b, c, 0, 0, 0);
}
template <typename V, typename = void>
struct M32Takes : std::false_type {};
template <typename V>
struct M32Takes<V, std::void_t<decltype(__builtin_amdgcn_mfma_f32_32x32x16_bf16(
    std::declval<V>(), std::declval<V>(), std::declval<f32x16>(), 0, 0, 0))>>
    : std::true_type {};

__device__ __forceinline__ f32x16 MFMA32(uint4 a, uint4 b, f32x16 c) {
  if constexpr (M32Takes<bf16x8>::value) {
    return mfma32_call(__builtin_bit_cast(bf16x8, a), __builtin_bit_cast(bf16x8, b), c);
  } else {
    return mfma32_call(__builtin_bit_cast(s16x8, a), __builtin_bit_cast(s16x8, b), c);
  }
}

// ---------------- f32 -> bf16 via native casts (compiler emits cvt_pk) ----
__device__ __forceinline__ uint4 pk8(float4 x, float4 y) {
  bf16x8 v = {(__bf16)x.x, (__bf16)x.y, (__bf16)x.z, (__bf16)x.w,
              (__bf16)y.x, (__bf16)y.y, (__bf16)y.z, (__bf16)y.w};
  return __builtin_bit_cast(uint4, v);
}
__device__ __forceinline__ unsigned pk2n(float a, float b) {
  unsigned short ua = __builtin_bit_cast(unsigned short, (__bf16)a);
  unsigned short ub = __builtin_bit_cast(unsigned short, (__bf16)b);
  return (unsigned)ua | ((unsigned)ub << 16);
}

// ---------------- problem constants ----------------
constexpr int TS  = 2304;
constexpr int DH  = 64;
constexpr int QTB = 128;         // q rows per block (32 per wave, 4 waves)
constexpr int NQB = TS / QTB;    // 18
constexpr int KVB = 64;          // kv rows per step
constexpr int STR = 72;          // LDS row stride (shorts): 144B (quarter-wave bank-distinct)
constexpr float QSCL = 0.125f * 1.4426950408889634f;  // 1/sqrt(64) * log2(e)
constexpr float THR  = 8.0f * 1.4426950408889634f;    // defer-rescale, log2 units
constexpr float NEGBIG = -3.0e38f;

// Pure-causal L-former (round-0 analysis). Swapped-QK structure:
//   S^T[kv][q] = mfma32(A=K, B=Q^T)  -> lane owns full P-column for q=lane&31
//   softmax: in-lane trees + one shfl_xor(32); P->A-frag in-register (no LDS)
//   O[q][d]  = mfma32(A=P, B=V^T-read); C/D rows rescaled via rare bpermute gather.
// LDS regions (shorts): lk0@0, lk1@4608, vt0@9216, vt1@13824 (stride 72/row).
__global__ __launch_bounds__(256, 3) void lformer_attn(
    const float* __restrict__ Qm, const float* __restrict__ Km,
    const float* __restrict__ Vm, float* __restrict__ Om) {
  __shared__ short sh[4 * 64 * STR];   // 36,864 B

  const int bid = blockIdx.x;
  const int qb  = (NQB - 1) - (bid >> 5);  // heavy q-blocks first
  const int bh  = bid & 31;
  const int tid = threadIdx.x;
  const int w    = tid >> 6;     // 0..3
  const int lane = tid & 63;
  const int ql   = lane & 31;
  const int hi   = lane >> 5;

  const size_t base = (size_t)bh * TS * DH;
  const int q0  = qb * QTB;
  const int qw0 = q0 + 32 * w;   // this wave's first q row

  // staging maps
  const int kr0 = tid >> 3;         // K rows 0..31 (+32)
  const int kcf = (tid & 7) * 8;    // K 8-float chunk
  // V^T: thread loads V[kv=it*16+4w+rr][d=lane], writes vt[lane][kv-quad]

  const int nkv = (q0 + QTB) / KVB;       // 2*qb + 2

  // ---- T14 prefetch registers ----
  float4 kpre[2][2];
  float  vpre[4][4];

  auto issue = [&](int step) {
    const int kv0 = step * KVB;
#pragma unroll
    for (int h = 0; h < 2; ++h) {
      const float* kp = Km + base + (size_t)(kv0 + kr0 + 32 * h) * DH + kcf;
      kpre[h][0] = *(const float4*)kp;
      kpre[h][1] = *(const float4*)(kp + 4);
    }
#pragma unroll
    for (int it = 0; it < 4; ++it) {
      const float* vp = Vm + base + (size_t)(kv0 + it * 16 + 4 * w) * DH + lane;
      vpre[it][0] = vp[0];
      vpre[it][1] = vp[DH];
      vpre[it][2] = vp[2 * DH];
      vpre[it][3] = vp[3 * DH];
    }
  };

  auto flush = [&](int buf) {
    short* lkb = sh + buf * 4608;
#pragma unroll
    for (int h = 0; h < 2; ++h) {
      const int row = kr0 + 32 * h;
      *(uint4*)&lkb[row * STR + kcf] = pk8(kpre[h][0], kpre[h][1]);
    }
    short* vtb = sh + 9216 + buf * 4608;
#pragma unroll
    for (int it = 0; it < 4; ++it) {
      const int r = it * 16 + 4 * w;
      *(uint2*)&vtb[lane * STR + r] =
          make_uint2(pk2n(vpre[it][0], vpre[it][1]),
                     pk2n(vpre[it][2], vpre[it][3]));
    }
  };

  // ---- Q fragments (B-operand of S^T): lane holds Q[qw0+ql][16c+8hi .. +8) ----
  issue(0);                               // K/V loads fly under Q packing
  uint4 qf[4];
  {
    const float* qp = Qm + base + (size_t)(qw0 + ql) * DH;
#pragma unroll
    for (int c = 0; c < 4; ++c) {
      const int d = 16 * c + 8 * hi;
      float4 x = *(const float4*)(qp + d);
      float4 y = *(const float4*)(qp + d + 4);
      x.x *= QSCL; x.y *= QSCL; x.z *= QSCL; x.w *= QSCL;
      y.x *= QSCL; y.y *= QSCL; y.z *= QSCL; y.w *= QSCL;
      qf[c] = pk8(x, y);
    }
  }

  f32x16 acc[2] = {};            // O[q][d]: C/D rows=q, cols=d (2 d-tiles)
  float mrow = NEGBIG;           // per-lane softmax state for q = qw0+ql
  float lrow = 0.f;

  const int kb = ql * STR + 8 * hi;   // shared per-lane LDS read base (shorts)

  auto compute = [&](int step, int buf, auto masked) {
    const int kv0 = step * KVB;
    const short* lkb = sh + buf * 4608;
    const short* vtb = sh + 9216 + buf * 4608;

    // ---- S^T = K · Q^T : 2 kv-halves x 4 k-chunks ----
    f32x16 s[2];
#pragma unroll
    for (int nt = 0; nt < 2; ++nt) {
      f32x16 sa = {};
#pragma unroll
      for (int c = 0; c < 4; ++c) {
        const uint4 kf = *(const uint4*)&lkb[kb + nt * 32 * STR + c * 16];
        sa = MFMA32(kf, qf[c], sa);
      }
      s[nt] = sa;
    }

    // ---- mask (diag tiles only) + flatten: p[8*kc + j] = kv 16kc+j+4hi ----
    float p[32];
    const int qg = qw0 + ql;
#pragma unroll
    for (int nt = 0; nt < 2; ++nt)
#pragma unroll
      for (int r = 0; r < 16; ++r) {
        float x = s[nt][r];
        if constexpr (decltype(masked)::value) {
          const int kvg = kv0 + nt * 32 + (r & 3) + 8 * (r >> 2) + 4 * hi;
          x = (kvg > qg) ? NEGBIG : x;
        }
        p[nt * 16 + r] = x;
      }

    // ---- in-lane max tree + cross-half ----
    float t[16];
#pragma unroll
    for (int r = 0; r < 16; ++r) t[r] = fmaxf(p[r], p[r + 16]);
#pragma unroll
    for (int r = 0; r < 8; ++r) t[r] = fmaxf(t[r], t[r + 8]);
#pragma unroll
    for (int r = 0; r < 4; ++r) t[r] = fmaxf(t[r], t[r + 4]);
    float mx = fmaxf(fmaxf(t[0], t[1]), fmaxf(t[2], t[3]));
    mx = fmaxf(mx, __shfl_xor(mx, 32, 64));

    // ---- defer-rescale (T13): rare gather-based O rescale ----
    if (!__all(mx - mrow <= THR)) {
      const float mn = fmaxf(mrow, mx);
      const float a  = exp2f(mrow - mn);
      mrow = mn;
      lrow *= a;
#pragma unroll
      for (int r = 0; r < 16; ++r) {
        const float ar = __shfl(a, (r & 3) + 8 * (r >> 2) + 4 * hi, 64);
        acc[0][r] *= ar;
        acc[1][r] *= ar;
      }
    }

    // ---- P = exp2(S - m); in-lane sum + cross-half ----
#pragma unroll
    for (int r = 0; r < 32; ++r) p[r] = exp2f(p[r] - mrow);
    {
      float u[16];
#pragma unroll
      for (int r = 0; r < 16; ++r) u[r] = p[r] + p[r + 16];
#pragma unroll
      for (int r = 0; r < 8; ++r) u[r] += u[r + 8];
#pragma unroll
      for (int r = 0; r < 4; ++r) u[r] += u[r + 4];
      float ss = (u[0] + u[1]) + (u[2] + u[3]);
      lrow += ss + __shfl_xor(ss, 32, 64);
    }

    // ---- P -> A-frags in-register; O += P·V per kv-chunk ----
#pragma unroll
    for (int kc = 0; kc < 4; ++kc) {
      const int b = 8 * kc;
      const unsigned d0 = pk2n(p[b + 0], p[b + 1]);
      const unsigned d1 = pk2n(p[b + 2], p[b + 3]);
      const unsigned d2 = pk2n(p[b + 4], p[b + 5]);
      const unsigned d3 = pk2n(p[b + 6], p[b + 7]);
      const unsigned r1 = __shfl_xor((int)(hi ? d0 : d2), 32, 64);
      const unsigned r2 = __shfl_xor((int)(hi ? d1 : d3), 32, 64);
      uint4 pa;
      pa.x = hi ? r1 : d0;
      pa.y = hi ? r2 : d1;
      pa.z = hi ? d2 : r1;
      pa.w = hi ? d3 : r2;
#pragma unroll
      for (int dt = 0; dt < 2; ++dt) {
        const uint4 vf = *(const uint4*)&vtb[kb + dt * 32 * STR + kc * 16];
        acc[dt] = MFMA32(pa, vf, acc[dt]);
      }
    }
  };

  // ---- pipelined main loop: one barrier per step ----
  flush(0);
  __syncthreads();
  int buf = 0;
  for (int step = 0; step < nkv - 1; ++step) {
    issue(step + 1);
    if (step * KVB + KVB - 1 > qw0) compute(step, buf, std::true_type{});
    else                            compute(step, buf, std::false_type{});
    flush(buf ^ 1);
    __syncthreads();
    buf ^= 1;
  }
  if ((nkv - 1) * KVB <= qw0 + 31) compute(nkv - 1, buf, std::true_type{});

  // ---- epilogue: gather 1/l per C/D row, coalesced stores ----
  const float inv = 1.0f / lrow;
  float* op = Om + base;
#pragma unroll
  for (int r = 0; r < 16; ++r) {
    const int row = (r & 3) + 8 * (r >> 2) + 4 * hi;
    const float ir = __shfl(inv, row, 64);
#pragma unroll
    for (int dt = 0; dt < 2; ++dt)
      op[(size_t)(qw0 + row) * DH + 32 * dt + ql] = acc[dt][r] * ir;
  }
}

extern "C" void kernel_launch(void* const* d_in, const int* in_sizes, int n_in,
                              void* d_out, int out_size, void* d_ws, size_t ws_size,
                              hipStream_t stream) {
  (void)in_sizes; (void)n_in; (void)d_ws; (void)ws_size; (void)out_size;
  const float* q = (const float*)d_in[0];
  const float* k = (const float*)d_in[1];
  const float* v = (const float*)d_in[2];
  float* o = (float*)d_out;
  lformer_attn<<<dim3(NQB * 32), dim3(256), 0, stream>>>(q, k, v, o);
}